// Round 9
// baseline (321.806 us; speedup 1.0000x reference)
//
#include <hip/hip_runtime.h>
#include <hip/hip_bf16.h>
#include <math.h>

// HGNNExpertCoupler, algebraically collapsed:
//   all_pairs hypergraph => M = (6I+J)/14 doubly stochastic; mean-pool kills it:
//   out = LN(gelu( meanE(x) @ (Wc*W2*W1)^T + Wc*(W2*b1+b2)+cb ))
// R9: fat-block gemm_ln. R7 stagger NULL -> hotspot theory dead. New theory:
//     per-XCD L2 contention ~ #CUs streaming the 512KB wcomb (32/XCD before).
//     Now 64 blocks x 128 tokens: A-tile 128KB LDS, wcomb restream 256->32 MB,
//     8 CUs/XCD (same density as the believed-fast prep GEMMs). If still slow,
//     it surfaces in rocprof top-5 with its own counters.
// 4 launches: prep1 {W1^T cast | W2/Wc cast | mv1 | POOL meanE->g bf16}
//             prep2 {w21t = W1T x_NT W2 | cbias = Wc*tmpv+cb}
//             prep3 {wcomb = WcB x_NT w21t}
//             gemm_ln {g @ wcomb^T + cbias -> gelu -> LN}

#define DD 512
#define NTOK 8192  // B*L

typedef short s16x8 __attribute__((ext_vector_type(8)));
typedef short s16x4 __attribute__((ext_vector_type(4)));
typedef float f32x4 __attribute__((ext_vector_type(4)));

static __device__ __forceinline__ short f2bf(float x) {
  unsigned u = __builtin_bit_cast(unsigned, x);
  unsigned r = (u + 0x7fffu + ((u >> 16) & 1u)) >> 16;
  return (short)r;
}

// ---------- helpers ----------
static __device__ __forceinline__ void do_cast4(const float* __restrict__ src,
                                                short* __restrict__ dst, int i) {
  int j = i << 2;
  f32x4 v = *(const f32x4*)(src + j);
  s16x4 o;
  o[0] = f2bf(v[0]); o[1] = f2bf(v[1]); o[2] = f2bf(v[2]); o[3] = f2bf(v[3]);
  *(s16x4*)(dst + j) = o;
}

static __device__ __forceinline__ void do_mv(const float* __restrict__ M,
                                             const float* __restrict__ v,
                                             const float* __restrict__ add,
                                             float* __restrict__ outv,
                                             int gtid) {
  int w = gtid >> 6, l = gtid & 63;
  if (w >= DD) return;
  float s = 0.f;
  for (int k = l; k < DD; k += 64) s += M[(size_t)w * DD + k] * v[k];
#pragma unroll
  for (int m = 32; m; m >>= 1) s += __shfl_xor(s, m);
  if (l == 0) outv[w] = s + add[w];
}

// prep1: casttr(W1) [0,256) | cast W2,Wc [256,768) | mv1 [768,896) | pool [896,2944)
__global__ __launch_bounds__(256) void prep1_kernel(
    const float* __restrict__ w1, const float* __restrict__ w2,
    const float* __restrict__ wc, const float* __restrict__ b1,
    const float* __restrict__ b2, const float* __restrict__ x,
    short* __restrict__ w1t, short* __restrict__ w2b, short* __restrict__ wcb,
    float* __restrict__ tmpv, short* __restrict__ g) {
  int b = blockIdx.x, tid = threadIdx.x;
  if (b >= 896) {  // POOL: g[n,d] = meanE x[n,e,d] -> bf16. 2048 blocks.
    int i0 = (b - 896) * 256 + tid;  // f32x4-chunk id
#pragma unroll
    for (int j = 0; j < 2; ++j) {
      int ci = i0 + j * 524288;  // 2 chunks/thread, 1,048,576 total
      int n = ci >> 7;
      int d4 = (ci & 127) << 2;
      const float* p = x + (size_t)n * (8 * DD) + d4;
      f32x4 s = {0.f, 0.f, 0.f, 0.f};
#pragma unroll
      for (int e = 0; e < 8; ++e) s += *(const f32x4*)(p + e * DD);
      s *= 0.125f;
      s16x4 o;
      o[0] = f2bf(s[0]); o[1] = f2bf(s[1]); o[2] = f2bf(s[2]); o[3] = f2bf(s[3]);
      *(s16x4*)(g + (size_t)n * DD + d4) = o;
    }
  } else if (b < 256) {  // transpose-cast W1 -> W1T bf16, 32x32 tiles
    __shared__ float t[32][33];
    int bx = b & 15, by = b >> 4;
    int tx = tid & 31, ty8 = tid >> 5;
    int r0 = by * 32, c0 = bx * 32;
#pragma unroll
    for (int j = 0; j < 4; ++j) {
      int r = ty8 * 4 + j;
      t[r][tx] = w1[(size_t)(r0 + r) * DD + c0 + tx];
    }
    __syncthreads();
#pragma unroll
    for (int j = 0; j < 4; ++j) {
      int r = ty8 * 4 + j;
      w1t[(size_t)(c0 + r) * DD + r0 + tx] = f2bf(t[tx][r]);
    }
  } else if (b < 768) {  // straight casts
    int i = (b - 256) * 256 + tid;
    if (i < 65536) do_cast4(w2, w2b, i);
    else           do_cast4(wc, wcb, i - 65536);
  } else {  // tmpv = W2*b1 + b2
    do_mv(w2, b1, b2, tmpv, (b - 768) * 256 + tid);
  }
}

// -------- NT GEMM body (512^3): Out[m,n] = sum_k A[m,k]*B[n,k], 64 blocks ---
static __device__ __forceinline__ void do_wgemm(const short* __restrict__ A,
                                                const short* __restrict__ B,
                                                short* __restrict__ Out,
                                                int b, int tid) {
  int w = tid >> 6, l = tid & 63;
  int lr = l & 15, lg = l >> 4;
  int m0 = (b >> 3) * 64 + w * 16;
  int n0 = (b & 7) * 64;
  f32x4 acc[4] = {};
  const short* ap = A + (size_t)(m0 + lr) * DD + 8 * lg;
  const short* bp = B + (size_t)(n0 + lr) * DD + 8 * lg;
#pragma unroll
  for (int k0 = 0; k0 < DD; k0 += 32) {
    s16x8 a = *(const s16x8*)(ap + k0);
#pragma unroll
    for (int f = 0; f < 4; ++f) {
      s16x8 bb = *(const s16x8*)(bp + (size_t)f * 16 * DD + k0);
      acc[f] = __builtin_amdgcn_mfma_f32_16x16x32_bf16(a, bb, acc[f], 0, 0, 0);
    }
  }
#pragma unroll
  for (int f = 0; f < 4; ++f)
#pragma unroll
    for (int r = 0; r < 4; ++r)
      Out[(size_t)(m0 + lg * 4 + r) * DD + n0 + f * 16 + lr] = f2bf(acc[f][r]);
}

// ---------- prep2: wgemm1 [0,64) | mv2 [64,192) ----------
__global__ __launch_bounds__(256) void prep2_kernel(
    const short* __restrict__ w1t, const short* __restrict__ w2b,
    short* __restrict__ w21t, const float* __restrict__ wc,
    const float* __restrict__ tmpv, const float* __restrict__ cb,
    float* __restrict__ cbias) {
  int b = blockIdx.x, tid = threadIdx.x;
  if (b < 64) do_wgemm(w1t, w2b, w21t, b, tid);          // (W2*W1)^T
  else        do_mv(wc, tmpv, cb, cbias, (b - 64) * 256 + tid);
}

// ---------- prep3: wcomb = Wc x_NT w21t = Wc*W2*W1 (row-major [o][d]) -------
__global__ __launch_bounds__(256) void prep3_kernel(const short* __restrict__ wcb,
                                                    const short* __restrict__ w21t,
                                                    short* __restrict__ wcomb) {
  do_wgemm(wcb, w21t, wcomb, blockIdx.x, threadIdx.x);
}

// ---- gemm_ln v2: fat blocks. 64 blocks x 512 thr; block = 128 tokens x 512.
// A-tile 128KB XOR-swizzled LDS; per wave 64 cols, 8 m-subtiles, acc[8][4].
// B loaded once per block per K-step, reused across 8 m -> 32 MFMA / 4 B-loads.
__global__ __launch_bounds__(512, 2) void gemm_ln_kernel(
    const short* __restrict__ g, const short* __restrict__ wcomb,
    const float* __restrict__ cbias, const float* __restrict__ gamma,
    const float* __restrict__ beta, float* __restrict__ out) {
  __shared__ short As[128 * DD];    // 128 KB, XOR-swizzled rows
  __shared__ float red[128][8][2];  // 8 KB: per-row per-wave {sum, sumsq}
  int tid = threadIdx.x;
  int w = tid >> 6, l = tid & 63;
  int lr = l & 15, lg = l >> 4;
  int m0 = blockIdx.x * 128;

  // stage A tile: 128 rows x 1KB, linear global read, swizzled LDS write
  {
    const char* gs = (const char*)(g + (size_t)m0 * DD);
    char* ls = (char*)As;
#pragma unroll
    for (int j = 0; j < 16; ++j) {
      int ci = tid + 512 * j;  // 8192 16B-chunks
      int row = ci >> 6;
      int bo = (ci & 63) << 4;
      s16x8 v = *(const s16x8*)(gs + row * 1024 + bo);
      *(s16x8*)(ls + row * 1024 + (bo ^ ((row & 7) << 4))) = v;
    }
  }
  __syncthreads();

  f32x4 acc[8][4] = {};
  const short* bbase = wcomb + (size_t)(w * 64 + lr) * DD + 8 * lg;
  const char* lsc = (const char*)As;
  for (int k0 = 0; k0 < DD; k0 += 32) {
    int kb = (k0 + 8 * lg) * 2;
    s16x8 bb[4];
#pragma unroll
    for (int f = 0; f < 4; ++f)
      bb[f] = *(const s16x8*)(bbase + (size_t)f * 16 * DD + k0);
#pragma unroll
    for (int m = 0; m < 8; ++m) {
      int row = m * 16 + lr;
      s16x8 a = *(const s16x8*)(lsc + row * 1024 + (kb ^ ((row & 7) << 4)));
#pragma unroll
      for (int f = 0; f < 4; ++f)
        acc[m][f] = __builtin_amdgcn_mfma_f32_16x16x32_bf16(a, bb[f], acc[m][f], 0, 0, 0);
    }
  }

  // epilogue: +cbias, exact gelu, per-row LN over the 512 outs
  int cbase = w * 64 + lr;
  float cbv[4];
#pragma unroll
  for (int f = 0; f < 4; ++f) cbv[f] = cbias[cbase + f * 16];

  float s1[8][4] = {}, s2[8][4] = {};
#pragma unroll
  for (int m = 0; m < 8; ++m)
#pragma unroll
    for (int f = 0; f < 4; ++f)
#pragma unroll
      for (int r = 0; r < 4; ++r) {
        float xx = acc[m][f][r] + cbv[f];
        float z = 0.5f * xx * (1.0f + erff(xx * 0.70710678118f));
        acc[m][f][r] = z;
        s1[m][r] += z;
        s2[m][r] += z * z;
      }
  // reduce across 16 lr lanes (cols within the wave)
#pragma unroll
  for (int msk = 1; msk < 16; msk <<= 1)
#pragma unroll
    for (int m = 0; m < 8; ++m)
#pragma unroll
      for (int r = 0; r < 4; ++r) {
        s1[m][r] += __shfl_xor(s1[m][r], msk);
        s2[m][r] += __shfl_xor(s2[m][r], msk);
      }
  if (lr == 0) {
#pragma unroll
    for (int m = 0; m < 8; ++m)
#pragma unroll
      for (int r = 0; r < 4; ++r) {
        int row = m * 16 + lg * 4 + r;
        red[row][w][0] = s1[m][r];
        red[row][w][1] = s2[m][r];
      }
  }
  __syncthreads();
#pragma unroll
  for (int m = 0; m < 8; ++m)
#pragma unroll
    for (int r = 0; r < 4; ++r) {
      int row = m * 16 + lg * 4 + r;
      float t1 = 0.f, t2 = 0.f;
#pragma unroll
      for (int ww = 0; ww < 8; ++ww) {
        t1 += red[row][ww][0];
        t2 += red[row][ww][1];
      }
      float mu = t1 * (1.0f / 512.0f);
      float var = t2 * (1.0f / 512.0f) - mu * mu;
      float rs = rsqrtf(var + 1e-5f);
      float* op = out + (size_t)(m0 + row) * DD;
#pragma unroll
      for (int f = 0; f < 4; ++f) {
        int c = cbase + f * 16;
        op[c] = (acc[m][f][r] - mu) * rs * gamma[c] + beta[c];
      }
    }
}

extern "C" void kernel_launch(void* const* d_in, const int* in_sizes, int n_in,
                              void* d_out, int out_size, void* d_ws, size_t ws_size,
                              hipStream_t stream) {
  const float* x   = (const float*)d_in[0];  // [8,1024,8,512]
  const float* hw  = (const float*)d_in[1];  // [2,512,512]
  const float* hb  = (const float*)d_in[2];  // [2,512]
  const float* cw  = (const float*)d_in[3];  // [512,512]
  const float* cb  = (const float*)d_in[4];  // [512]
  const float* gam = (const float*)d_in[5];
  const float* bet = (const float*)d_in[6];
  float* out = (float*)d_out;

  char* ws = (char*)d_ws;
  short* g     = (short*)ws; ws += (size_t)NTOK * DD * 2;  // 8 MB
  short* w1t   = (short*)ws; ws += DD * DD * 2;
  short* w2b   = (short*)ws; ws += DD * DD * 2;
  short* wcb   = (short*)ws; ws += DD * DD * 2;
  short* w21t  = (short*)ws; ws += DD * DD * 2;
  short* wcomb = (short*)ws; ws += DD * DD * 2;
  float* tmpv  = (float*)ws; ws += DD * 4;
  float* cbias = (float*)ws; ws += DD * 4;

  const float* W1 = hw;
  const float* W2 = hw + DD * DD;
  const float* b1 = hb;
  const float* b2 = hb + DD;

  prep1_kernel<<<2944, 256, 0, stream>>>(W1, W2, cw, b1, b2, x,
                                         w1t, w2b, wcb, tmpv, g);
  prep2_kernel<<<192, 256, 0, stream>>>(w1t, w2b, w21t, cw, tmpv, cb, cbias);
  prep3_kernel<<<64, 256, 0, stream>>>(wcb, w21t, wcomb);
  gemm_ln_kernel<<<64, 512, 0, stream>>>(g, wcomb, cbias, gam, bet, out);
}

// Round 10
// 250.935 us; speedup vs baseline: 1.2824x; 1.2824x over previous
//
#include <hip/hip_runtime.h>
#include <hip/hip_bf16.h>
#include <math.h>

// HGNNExpertCoupler, algebraically collapsed:
//   all_pairs hypergraph => M = (6I+J)/14 doubly stochastic; mean-pool kills it:
//   out = LN(gelu( meanE(x) @ (Wc*W2*W1)^T + Wc*(W2*b1+b2)+cb ))
// R10: gemm_ln v3. R9 post-mortem: acc[8][4] spilled (VGPR capped 128,
//     WRITE_SIZE 45MB vs 16MB out) + 64/256 CUs idle -> experiment poisoned.
//     Now 256 blocks x 32 tokens x 512 thr: acc[2][4] (no spill), B regs
//     reused across 2 m-subtiles -> wcomb L2 restream 256->128 MB, all CUs hot.
// 4 launches: prep1 {W1^T cast | W2/Wc cast | mv1 | POOL meanE->g bf16}
//             prep2 {w21t = W1T x_NT W2 | cbias = Wc*tmpv+cb}
//             prep3 {wcomb = WcB x_NT w21t}
//             gemm_ln {g @ wcomb^T + cbias -> gelu -> LN}

#define DD 512
#define NTOK 8192  // B*L

typedef short s16x8 __attribute__((ext_vector_type(8)));
typedef short s16x4 __attribute__((ext_vector_type(4)));
typedef float f32x4 __attribute__((ext_vector_type(4)));

static __device__ __forceinline__ short f2bf(float x) {
  unsigned u = __builtin_bit_cast(unsigned, x);
  unsigned r = (u + 0x7fffu + ((u >> 16) & 1u)) >> 16;
  return (short)r;
}

// ---------- helpers ----------
static __device__ __forceinline__ void do_cast4(const float* __restrict__ src,
                                                short* __restrict__ dst, int i) {
  int j = i << 2;
  f32x4 v = *(const f32x4*)(src + j);
  s16x4 o;
  o[0] = f2bf(v[0]); o[1] = f2bf(v[1]); o[2] = f2bf(v[2]); o[3] = f2bf(v[3]);
  *(s16x4*)(dst + j) = o;
}

static __device__ __forceinline__ void do_mv(const float* __restrict__ M,
                                             const float* __restrict__ v,
                                             const float* __restrict__ add,
                                             float* __restrict__ outv,
                                             int gtid) {
  int w = gtid >> 6, l = gtid & 63;
  if (w >= DD) return;
  float s = 0.f;
  for (int k = l; k < DD; k += 64) s += M[(size_t)w * DD + k] * v[k];
#pragma unroll
  for (int m = 32; m; m >>= 1) s += __shfl_xor(s, m);
  if (l == 0) outv[w] = s + add[w];
}

// prep1: casttr(W1) [0,256) | cast W2,Wc [256,768) | mv1 [768,896) | pool [896,2944)
__global__ __launch_bounds__(256) void prep1_kernel(
    const float* __restrict__ w1, const float* __restrict__ w2,
    const float* __restrict__ wc, const float* __restrict__ b1,
    const float* __restrict__ b2, const float* __restrict__ x,
    short* __restrict__ w1t, short* __restrict__ w2b, short* __restrict__ wcb,
    float* __restrict__ tmpv, short* __restrict__ g) {
  int b = blockIdx.x, tid = threadIdx.x;
  if (b >= 896) {  // POOL: g[n,d] = meanE x[n,e,d] -> bf16. 2048 blocks.
    int i0 = (b - 896) * 256 + tid;  // f32x4-chunk id
#pragma unroll
    for (int j = 0; j < 2; ++j) {
      int ci = i0 + j * 524288;  // 2 chunks/thread, 1,048,576 total
      int n = ci >> 7;
      int d4 = (ci & 127) << 2;
      const float* p = x + (size_t)n * (8 * DD) + d4;
      f32x4 s = {0.f, 0.f, 0.f, 0.f};
#pragma unroll
      for (int e = 0; e < 8; ++e) s += *(const f32x4*)(p + e * DD);
      s *= 0.125f;
      s16x4 o;
      o[0] = f2bf(s[0]); o[1] = f2bf(s[1]); o[2] = f2bf(s[2]); o[3] = f2bf(s[3]);
      *(s16x4*)(g + (size_t)n * DD + d4) = o;
    }
  } else if (b < 256) {  // transpose-cast W1 -> W1T bf16, 32x32 tiles
    __shared__ float t[32][33];
    int bx = b & 15, by = b >> 4;
    int tx = tid & 31, ty8 = tid >> 5;
    int r0 = by * 32, c0 = bx * 32;
#pragma unroll
    for (int j = 0; j < 4; ++j) {
      int r = ty8 * 4 + j;
      t[r][tx] = w1[(size_t)(r0 + r) * DD + c0 + tx];
    }
    __syncthreads();
#pragma unroll
    for (int j = 0; j < 4; ++j) {
      int r = ty8 * 4 + j;
      w1t[(size_t)(c0 + r) * DD + r0 + tx] = f2bf(t[tx][r]);
    }
  } else if (b < 768) {  // straight casts
    int i = (b - 256) * 256 + tid;
    if (i < 65536) do_cast4(w2, w2b, i);
    else           do_cast4(wc, wcb, i - 65536);
  } else {  // tmpv = W2*b1 + b2
    do_mv(w2, b1, b2, tmpv, (b - 768) * 256 + tid);
  }
}

// -------- NT GEMM body (512^3): Out[m,n] = sum_k A[m,k]*B[n,k], 64 blocks ---
static __device__ __forceinline__ void do_wgemm(const short* __restrict__ A,
                                                const short* __restrict__ B,
                                                short* __restrict__ Out,
                                                int b, int tid) {
  int w = tid >> 6, l = tid & 63;
  int lr = l & 15, lg = l >> 4;
  int m0 = (b >> 3) * 64 + w * 16;
  int n0 = (b & 7) * 64;
  f32x4 acc[4] = {};
  const short* ap = A + (size_t)(m0 + lr) * DD + 8 * lg;
  const short* bp = B + (size_t)(n0 + lr) * DD + 8 * lg;
#pragma unroll
  for (int k0 = 0; k0 < DD; k0 += 32) {
    s16x8 a = *(const s16x8*)(ap + k0);
#pragma unroll
    for (int f = 0; f < 4; ++f) {
      s16x8 bb = *(const s16x8*)(bp + (size_t)f * 16 * DD + k0);
      acc[f] = __builtin_amdgcn_mfma_f32_16x16x32_bf16(a, bb, acc[f], 0, 0, 0);
    }
  }
#pragma unroll
  for (int f = 0; f < 4; ++f)
#pragma unroll
    for (int r = 0; r < 4; ++r)
      Out[(size_t)(m0 + lg * 4 + r) * DD + n0 + f * 16 + lr] = f2bf(acc[f][r]);
}

// ---------- prep2: wgemm1 [0,64) | mv2 [64,192) ----------
__global__ __launch_bounds__(256) void prep2_kernel(
    const short* __restrict__ w1t, const short* __restrict__ w2b,
    short* __restrict__ w21t, const float* __restrict__ wc,
    const float* __restrict__ tmpv, const float* __restrict__ cb,
    float* __restrict__ cbias) {
  int b = blockIdx.x, tid = threadIdx.x;
  if (b < 64) do_wgemm(w1t, w2b, w21t, b, tid);          // (W2*W1)^T
  else        do_mv(wc, tmpv, cb, cbias, (b - 64) * 256 + tid);
}

// ---------- prep3: wcomb = Wc x_NT w21t = Wc*W2*W1 (row-major [o][d]) -------
__global__ __launch_bounds__(256) void prep3_kernel(const short* __restrict__ wcb,
                                                    const short* __restrict__ w21t,
                                                    short* __restrict__ wcomb) {
  do_wgemm(wcb, w21t, wcomb, blockIdx.x, threadIdx.x);
}

// ---- gemm_ln v3: 256 blocks x 512 thr; block = 32 tokens x 512 cols.
// Wave = 64 cols x 2 m-subtiles; acc[2][4] (32 VGPR, no spill); B regs
// reused across both m-subtiles -> wcomb L2 restream 128 MB total.
__global__ __launch_bounds__(512, 4) void gemm_ln_kernel(
    const short* __restrict__ g, const short* __restrict__ wcomb,
    const float* __restrict__ cbias, const float* __restrict__ gamma,
    const float* __restrict__ beta, float* __restrict__ out) {
  __shared__ short As[32 * DD];    // 32 KB, XOR-swizzled rows
  __shared__ float red[32][8][2];  // per-row per-wave {sum, sumsq}
  int tid = threadIdx.x;
  int w = tid >> 6, l = tid & 63;
  int lr = l & 15, lg = l >> 4;
  int m0 = blockIdx.x * 32;

  // stage A tile: 32 rows x 1KB, linear global read, swizzled LDS write
  {
    const char* gs = (const char*)(g + (size_t)m0 * DD);
    char* ls = (char*)As;
#pragma unroll
    for (int j = 0; j < 4; ++j) {
      int ci = tid + 512 * j;  // 2048 16B-chunks
      int row = ci >> 6;
      int bo = (ci & 63) << 4;
      s16x8 v = *(const s16x8*)(gs + row * 1024 + bo);
      *(s16x8*)(ls + row * 1024 + (bo ^ ((row & 7) << 4))) = v;
    }
  }
  __syncthreads();

  f32x4 acc[2][4] = {};
  const short* bbase = wcomb + (size_t)(w * 64 + lr) * DD + 8 * lg;
  const char* lsc = (const char*)As;
  for (int k0 = 0; k0 < DD; k0 += 32) {
    int kb = (k0 + 8 * lg) * 2;
    s16x8 bb[4];
#pragma unroll
    for (int f = 0; f < 4; ++f)
      bb[f] = *(const s16x8*)(bbase + (size_t)f * 16 * DD + k0);
#pragma unroll
    for (int m = 0; m < 2; ++m) {
      int row = m * 16 + lr;
      s16x8 a = *(const s16x8*)(lsc + row * 1024 + (kb ^ ((row & 7) << 4)));
#pragma unroll
      for (int f = 0; f < 4; ++f)
        acc[m][f] = __builtin_amdgcn_mfma_f32_16x16x32_bf16(a, bb[f], acc[m][f], 0, 0, 0);
    }
  }

  // epilogue: +cbias, exact gelu, per-row LN over the 512 outs
  int cbase = w * 64 + lr;
  float cbv[4];
#pragma unroll
  for (int f = 0; f < 4; ++f) cbv[f] = cbias[cbase + f * 16];

  float s1[2][4] = {}, s2[2][4] = {};
#pragma unroll
  for (int m = 0; m < 2; ++m)
#pragma unroll
    for (int f = 0; f < 4; ++f)
#pragma unroll
      for (int r = 0; r < 4; ++r) {
        float xx = acc[m][f][r] + cbv[f];
        float z = 0.5f * xx * (1.0f + erff(xx * 0.70710678118f));
        acc[m][f][r] = z;
        s1[m][r] += z;
        s2[m][r] += z * z;
      }
  // reduce across 16 lr lanes (cols within the wave)
#pragma unroll
  for (int msk = 1; msk < 16; msk <<= 1)
#pragma unroll
    for (int m = 0; m < 2; ++m)
#pragma unroll
      for (int r = 0; r < 4; ++r) {
        s1[m][r] += __shfl_xor(s1[m][r], msk);
        s2[m][r] += __shfl_xor(s2[m][r], msk);
      }
  if (lr == 0) {
#pragma unroll
    for (int m = 0; m < 2; ++m)
#pragma unroll
      for (int r = 0; r < 4; ++r) {
        int row = m * 16 + lg * 4 + r;
        red[row][w][0] = s1[m][r];
        red[row][w][1] = s2[m][r];
      }
  }
  __syncthreads();
#pragma unroll
  for (int m = 0; m < 2; ++m)
#pragma unroll
    for (int r = 0; r < 4; ++r) {
      int row = m * 16 + lg * 4 + r;
      float t1 = 0.f, t2 = 0.f;
#pragma unroll
      for (int ww = 0; ww < 8; ++ww) {
        t1 += red[row][ww][0];
        t2 += red[row][ww][1];
      }
      float mu = t1 * (1.0f / 512.0f);
      float var = t2 * (1.0f / 512.0f) - mu * mu;
      float rs = rsqrtf(var + 1e-5f);
      float* op = out + (size_t)(m0 + row) * DD;
#pragma unroll
      for (int f = 0; f < 4; ++f) {
        int c = cbase + f * 16;
        op[c] = (acc[m][f][r] - mu) * rs * gamma[c] + beta[c];
      }
    }
}

extern "C" void kernel_launch(void* const* d_in, const int* in_sizes, int n_in,
                              void* d_out, int out_size, void* d_ws, size_t ws_size,
                              hipStream_t stream) {
  const float* x   = (const float*)d_in[0];  // [8,1024,8,512]
  const float* hw  = (const float*)d_in[1];  // [2,512,512]
  const float* hb  = (const float*)d_in[2];  // [2,512]
  const float* cw  = (const float*)d_in[3];  // [512,512]
  const float* cb  = (const float*)d_in[4];  // [512]
  const float* gam = (const float*)d_in[5];
  const float* bet = (const float*)d_in[6];
  float* out = (float*)d_out;

  char* ws = (char*)d_ws;
  short* g     = (short*)ws; ws += (size_t)NTOK * DD * 2;  // 8 MB
  short* w1t   = (short*)ws; ws += DD * DD * 2;
  short* w2b   = (short*)ws; ws += DD * DD * 2;
  short* wcb   = (short*)ws; ws += DD * DD * 2;
  short* w21t  = (short*)ws; ws += DD * DD * 2;
  short* wcomb = (short*)ws; ws += DD * DD * 2;
  float* tmpv  = (float*)ws; ws += DD * 4;
  float* cbias = (float*)ws; ws += DD * 4;

  const float* W1 = hw;
  const float* W2 = hw + DD * DD;
  const float* b1 = hb;
  const float* b2 = hb + DD;

  prep1_kernel<<<2944, 256, 0, stream>>>(W1, W2, cw, b1, b2, x,
                                         w1t, w2b, wcb, tmpv, g);
  prep2_kernel<<<192, 256, 0, stream>>>(w1t, w2b, w21t, cw, tmpv, cb, cbias);
  prep3_kernel<<<64, 256, 0, stream>>>(wcb, w21t, wcomb);
  gemm_ln_kernel<<<256, 512, 0, stream>>>(g, wcomb, cbias, gam, bet, out);
}